// Round 2
// baseline (9819.996 us; speedup 1.0000x reference)
//
#include <hip/hip_runtime.h>
#include <math.h>

#define BLOCK 64

// ---------------- prep: pad W0 [27][128] -> [32][128] (zero rows),
//                        pad W4 [128][25] -> [128][28] (zero cols, 16B-aligned rows)
__global__ void prep_kernel(const float* __restrict__ W0, const float* __restrict__ W4,
                            float* __restrict__ W0p, float* __restrict__ W4p) {
    const int t = blockIdx.x * blockDim.x + threadIdx.x;
    if (t < 32 * 128) {
        const int k = t >> 7, j = t & 127;
        W0p[t] = (k < 27) ? W0[k * 128 + j] : 0.0f;
    }
    if (t < 128 * 28) {
        const int k = t / 28, j = t - k * 28;
        W4p[t] = (j < 25) ? W4[k * 25 + j] : 0.0f;
    }
}

// square-ish layer: IN in {32,128}, OUT=128, weight row stride 128, h k-major in LDS
template <int IN>
__device__ __forceinline__ void layer_sq(const float* __restrict__ W,
                                         const float* __restrict__ b,
                                         const float* __restrict__ hL,
                                         const int tid, float* __restrict__ o) {
#pragma unroll
    for (int c = 0; c < 4; ++c) {
        float* __restrict__ oc = o + c * 32;
#pragma unroll
        for (int j = 0; j < 32; ++j) oc[j] = b[c * 32 + j];
        float4 wA[8], wB[8];
        {
            const float4* r0 = (const float4*)(W + c * 32);
            const float4* r1 = (const float4*)(W + 128 + c * 32);
#pragma unroll
            for (int q = 0; q < 8; ++q) wA[q] = r0[q];
#pragma unroll
            for (int q = 0; q < 8; ++q) wB[q] = r1[q];
        }
        float h0 = hL[tid];
        float h1 = hL[64 + tid];
#pragma unroll 2
        for (int k = 0; k < IN - 2; k += 2) {
            const float hn0 = hL[(k + 2) * 64 + tid];
            const float hn1 = hL[(k + 3) * 64 + tid];
            const float4* rn0 = (const float4*)(W + (k + 2) * 128 + c * 32);
            const float4* rn1 = (const float4*)(W + (k + 3) * 128 + c * 32);
#pragma unroll
            for (int q = 0; q < 8; ++q) {
                const float4 w = wA[q];
                oc[q * 4 + 0] = fmaf(h0, w.x, oc[q * 4 + 0]);
                oc[q * 4 + 1] = fmaf(h0, w.y, oc[q * 4 + 1]);
                oc[q * 4 + 2] = fmaf(h0, w.z, oc[q * 4 + 2]);
                oc[q * 4 + 3] = fmaf(h0, w.w, oc[q * 4 + 3]);
                wA[q] = rn0[q];
            }
#pragma unroll
            for (int q = 0; q < 8; ++q) {
                const float4 w = wB[q];
                oc[q * 4 + 0] = fmaf(h1, w.x, oc[q * 4 + 0]);
                oc[q * 4 + 1] = fmaf(h1, w.y, oc[q * 4 + 1]);
                oc[q * 4 + 2] = fmaf(h1, w.z, oc[q * 4 + 2]);
                oc[q * 4 + 3] = fmaf(h1, w.w, oc[q * 4 + 3]);
                wB[q] = rn1[q];
            }
            h0 = hn0;
            h1 = hn1;
        }
        // peel: last two rows already resident in wA/wB, h0/h1
#pragma unroll
        for (int q = 0; q < 8; ++q) {
            const float4 w = wA[q];
            oc[q * 4 + 0] = fmaf(h0, w.x, oc[q * 4 + 0]);
            oc[q * 4 + 1] = fmaf(h0, w.y, oc[q * 4 + 1]);
            oc[q * 4 + 2] = fmaf(h0, w.z, oc[q * 4 + 2]);
            oc[q * 4 + 3] = fmaf(h0, w.w, oc[q * 4 + 3]);
        }
#pragma unroll
        for (int q = 0; q < 8; ++q) {
            const float4 w = wB[q];
            oc[q * 4 + 0] = fmaf(h1, w.x, oc[q * 4 + 0]);
            oc[q * 4 + 1] = fmaf(h1, w.y, oc[q * 4 + 1]);
            oc[q * 4 + 2] = fmaf(h1, w.z, oc[q * 4 + 2]);
            oc[q * 4 + 3] = fmaf(h1, w.w, oc[q * 4 + 3]);
        }
    }
}

// output layer: IN=128, padded OUT=28 (first 25 real), weight row stride 28
__device__ __forceinline__ void layer_out(const float* __restrict__ W,
                                          const float* __restrict__ b4,
                                          const float* __restrict__ hL,
                                          const int tid, float* __restrict__ o) {
#pragma unroll
    for (int j = 0; j < 25; ++j) o[j] = b4[j];
#pragma unroll
    for (int j = 25; j < 28; ++j) o[j] = 0.0f;
    float4 wA[7], wB[7];
    {
        const float4* r0 = (const float4*)(W);
        const float4* r1 = (const float4*)(W + 28);
#pragma unroll
        for (int q = 0; q < 7; ++q) wA[q] = r0[q];
#pragma unroll
        for (int q = 0; q < 7; ++q) wB[q] = r1[q];
    }
    float h0 = hL[tid];
    float h1 = hL[64 + tid];
#pragma unroll 2
    for (int k = 0; k < 126; k += 2) {
        const float hn0 = hL[(k + 2) * 64 + tid];
        const float hn1 = hL[(k + 3) * 64 + tid];
        const float4* rn0 = (const float4*)(W + (k + 2) * 28);
        const float4* rn1 = (const float4*)(W + (k + 3) * 28);
#pragma unroll
        for (int q = 0; q < 7; ++q) {
            const float4 w = wA[q];
            o[q * 4 + 0] = fmaf(h0, w.x, o[q * 4 + 0]);
            o[q * 4 + 1] = fmaf(h0, w.y, o[q * 4 + 1]);
            o[q * 4 + 2] = fmaf(h0, w.z, o[q * 4 + 2]);
            o[q * 4 + 3] = fmaf(h0, w.w, o[q * 4 + 3]);
            wA[q] = rn0[q];
        }
#pragma unroll
        for (int q = 0; q < 7; ++q) {
            const float4 w = wB[q];
            o[q * 4 + 0] = fmaf(h1, w.x, o[q * 4 + 0]);
            o[q * 4 + 1] = fmaf(h1, w.y, o[q * 4 + 1]);
            o[q * 4 + 2] = fmaf(h1, w.z, o[q * 4 + 2]);
            o[q * 4 + 3] = fmaf(h1, w.w, o[q * 4 + 3]);
            wB[q] = rn1[q];
        }
        h0 = hn0;
        h1 = hn1;
    }
#pragma unroll
    for (int q = 0; q < 7; ++q) {
        const float4 w = wA[q];
        o[q * 4 + 0] = fmaf(h0, w.x, o[q * 4 + 0]);
        o[q * 4 + 1] = fmaf(h0, w.y, o[q * 4 + 1]);
        o[q * 4 + 2] = fmaf(h0, w.z, o[q * 4 + 2]);
        o[q * 4 + 3] = fmaf(h0, w.w, o[q * 4 + 3]);
    }
#pragma unroll
    for (int q = 0; q < 7; ++q) {
        const float4 w = wB[q];
        o[q * 4 + 0] = fmaf(h1, w.x, o[q * 4 + 0]);
        o[q * 4 + 1] = fmaf(h1, w.y, o[q * 4 + 1]);
        o[q * 4 + 2] = fmaf(h1, w.z, o[q * 4 + 2]);
        o[q * 4 + 3] = fmaf(h1, w.w, o[q * 4 + 3]);
    }
}

__global__ __launch_bounds__(BLOCK, 2) void snarf_kernel(
    const float* __restrict__ xin, const float* __restrict__ bone_pts,
    const float* __restrict__ transforms, const float* __restrict__ delta_tf,
    const float* __restrict__ W0p, const float* __restrict__ b0,
    const float* __restrict__ W1, const float* __restrict__ b1,
    const float* __restrict__ W2, const float* __restrict__ b2,
    const float* __restrict__ W3, const float* __restrict__ b3,
    const float* __restrict__ W4p, const float* __restrict__ b4,
    float* __restrict__ out, int Npts) {
    __shared__ float hbuf[128 * BLOCK];  // k-major: hbuf[k*64+tid], 32 KiB
    const int tid = threadIdx.x;
    const int m = blockIdx.x * BLOCK + tid;
    const int M = Npts * 6;
    if (m >= M) return;
    const int n = m / 6;
    const int i = m - n * 6;

    const float tx = xin[n * 3 + 0], ty = xin[n * 3 + 1], tz = xin[n * 3 + 2];

    // ---- init candidate: i<5 -> i-th nearest bone's delta transform; i==5 -> identity
    float xk0, xk1, xk2;
    if (i < 5) {
        float dprev = -1.0f;
        int jprev = -1;
        for (int r = 0; r <= i; ++r) {
            float bd = 3.4028235e38f;
            int bj = 0;
            for (int j = 0; j < 24; ++j) {
                const float ax = tx - bone_pts[j * 3 + 0];
                const float ay = ty - bone_pts[j * 3 + 1];
                const float az = tz - bone_pts[j * 3 + 2];
                const float d = sqrtf(ax * ax + ay * ay + az * az);
                const bool taken = (d < dprev) || (d == dprev && j <= jprev);
                if (!taken && d < bd) { bd = d; bj = j; }
            }
            dprev = bd;
            jprev = bj;
        }
        const float* T = delta_tf + jprev * 16;
        xk0 = fmaf(T[0], tx, fmaf(T[1], ty, fmaf(T[2], tz, T[3])));
        xk1 = fmaf(T[4], tx, fmaf(T[5], ty, fmaf(T[6], tz, T[7])));
        xk2 = fmaf(T[8], tx, fmaf(T[9], ty, fmaf(T[10], tz, T[11])));
    } else {
        xk0 = tx; xk1 = ty; xk2 = tz;
    }

    // ---- Broyden state
    float gx0 = 0.f, gx1 = 0.f, gx2 = 0.f;
    float J00 = 1.f, J01 = 0.f, J02 = 0.f;
    float J10 = 0.f, J11 = 1.f, J12 = 0.f;
    float J20 = 0.f, J21 = 0.f, J22 = 1.f;
    float up0 = 0.f, up1 = 0.f, up2 = 0.f;
    float xo0 = xk0, xo1 = xk1, xo2 = xk2;
    float nopt = 0.f;
    float dx0 = 0.f, dx1 = 0.f, dx2 = 0.f;
    float dg0 = 0.f, dg1 = 0.f, dg2 = 0.f;
    bool mask = true;

    float o[128];

    int step = -1;  // -1 = init eval, 0..7 = Broyden steps, 8 = final eval
    while (step <= 8) {
        bool m3 = mask;
        if (step >= 0 && step < 8) {
            if (__ballot(mask) == 0ull) { step = 8; continue; }
            if (m3) {
                dx0 = up0; dx1 = up1; dx2 = up2;
                xk0 += dx0; xk1 += dx1; xk2 += dx2;
            }
        }
        float cx0 = xk0, cx1 = xk1, cx2 = xk2;
        if (step == 8) { cx0 = xo0; cx1 = xo1; cx2 = xo2; }

        // ======== g eval at (cx0,cx1,cx2) ========
        hbuf[0 * 64 + tid] = cx0;
        hbuf[1 * 64 + tid] = cx1;
        hbuf[2 * 64 + tid] = cx2;
#pragma unroll
        for (int s = 0; s < 4; ++s) {
            const float sc = (float)(1 << s);
            float s0, c0, s1, c1, s2, c2;
            sincosf(sc * cx0, &s0, &c0);
            sincosf(sc * cx1, &s1, &c1);
            sincosf(sc * cx2, &s2, &c2);
            hbuf[(3 + s * 3 + 0) * 64 + tid] = s0;
            hbuf[(3 + s * 3 + 1) * 64 + tid] = s1;
            hbuf[(3 + s * 3 + 2) * 64 + tid] = s2;
            hbuf[(15 + s * 3 + 0) * 64 + tid] = c0;
            hbuf[(15 + s * 3 + 1) * 64 + tid] = c1;
            hbuf[(15 + s * 3 + 2) * 64 + tid] = c2;
        }
#pragma unroll
        for (int k = 27; k < 32; ++k) hbuf[k * 64 + tid] = 0.0f;

        layer_sq<32>(W0p, b0, hbuf, tid, o);
#pragma unroll
        for (int k = 0; k < 128; ++k) hbuf[k * 64 + tid] = fmaxf(o[k], 0.0f);
        layer_sq<128>(W1, b1, hbuf, tid, o);
#pragma unroll
        for (int k = 0; k < 128; ++k) hbuf[k * 64 + tid] = fmaxf(o[k], 0.0f);
        layer_sq<128>(W2, b2, hbuf, tid, o);
#pragma unroll
        for (int k = 0; k < 128; ++k) hbuf[k * 64 + tid] = fmaxf(o[k], 0.0f);
        layer_sq<128>(W3, b3, hbuf, tid, o);
#pragma unroll
        for (int k = 0; k < 128; ++k) hbuf[k * 64 + tid] = fmaxf(o[k], 0.0f);
        layer_out(W4p, b4, hbuf, tid, o);

        // softmax(5 * logits) over 25
        float zm = -3.4028235e38f;
#pragma unroll
        for (int j = 0; j < 25; ++j) {
            o[j] = 5.0f * o[j];
            zm = fmaxf(zm, o[j]);
        }
        float ssum = 0.f;
#pragma unroll
        for (int j = 0; j < 25; ++j) {
            o[j] = expf(o[j] - zm);
            ssum += o[j];
        }
        const float inv = 1.0f / ssum;

        float tf[12];
#pragma unroll
        for (int r = 0; r < 12; ++r) tf[r] = 0.f;
#pragma unroll
        for (int j = 0; j < 24; ++j) {
            const float wj = o[j] * inv;
            const float* T = transforms + j * 16;
#pragma unroll
            for (int r = 0; r < 12; ++r) tf[r] = fmaf(wj, T[r], tf[r]);
        }
        {
            const float wj = o[24] * inv;  // identity transform
            tf[0] += wj; tf[5] += wj; tf[10] += wj;
        }
        const float r0 = fmaf(tf[0], cx0, fmaf(tf[1], cx1, fmaf(tf[2], cx2, tf[3])));
        const float r1 = fmaf(tf[4], cx0, fmaf(tf[5], cx1, fmaf(tf[6], cx2, tf[7])));
        const float r2 = fmaf(tf[8], cx0, fmaf(tf[9], cx1, fmaf(tf[10], cx2, tf[11])));
        // ======== end g eval ========

        if (step == 8) {
            out[(size_t)m * 3 + 0] = r0;
            out[(size_t)m * 3 + 1] = r1;
            out[(size_t)m * 3 + 2] = r2;
            float* xopt_out = out + (size_t)M * 3;
            xopt_out[(size_t)m * 3 + 0] = xo0;
            xopt_out[(size_t)m * 3 + 1] = xo1;
            xopt_out[(size_t)m * 3 + 2] = xo2;
            out[(size_t)M * 6 + m] = nopt;
            out[(size_t)M * 7 + m] = (nopt < 1e-5f) ? 1.0f : 0.0f;
            break;
        }

        const float g0 = r0 - tx, g1 = r1 - ty, g2 = r2 - tz;

        if (step == -1) {
            gx0 = g0; gx1 = g1; gx2 = g2;
            const float gn = sqrtf(g0 * g0 + g1 * g1 + g2 * g2);
            nopt = gn;
            up0 = -g0; up1 = -g1; up2 = -g2;  // Jinv = I
        } else {
            if (m3) {
                dg0 = g0 - gx0; dg1 = g1 - gx1; dg2 = g2 - gx2;
                gx0 += dg0; gx1 += dg1; gx2 += dg2;
            }
            const float gn = sqrtf(gx0 * gx0 + gx1 * gx1 + gx2 * gx2);
            const bool better = gn < nopt;
            if (better) {
                nopt = gn;
                xo0 = xk0; xo1 = xk1; xo2 = xk2;
            }
            mask = (nopt > 1e-5f) && (gn < 1.0f);

            const float v0 = dx0 * J00 + dx1 * J10 + dx2 * J20;
            const float v1 = dx0 * J01 + dx1 * J11 + dx2 * J21;
            const float v2 = dx0 * J02 + dx1 * J12 + dx2 * J22;
            const float Jd0 = J00 * dg0 + J01 * dg1 + J02 * dg2;
            const float Jd1 = J10 * dg0 + J11 * dg1 + J12 * dg2;
            const float Jd2 = J20 * dg0 + J21 * dg1 + J22 * dg2;
            const float a0 = dx0 - Jd0, a1 = dx1 - Jd1, a2 = dx2 - Jd2;
            float bden = v0 * dg0 + v1 * dg1 + v2 * dg2;
            bden += (bden >= 0.f) ? 1e-6f : -1e-6f;
            if (mask) {
                const float q0 = a0 / bden, q1 = a1 / bden, q2 = a2 / bden;
                J00 = fmaf(q0, v0, J00); J01 = fmaf(q0, v1, J01); J02 = fmaf(q0, v2, J02);
                J10 = fmaf(q1, v0, J10); J11 = fmaf(q1, v1, J11); J12 = fmaf(q1, v2, J12);
                J20 = fmaf(q2, v0, J20); J21 = fmaf(q2, v1, J21); J22 = fmaf(q2, v2, J22);
            }
            if (m3) {
                up0 = -(J00 * gx0 + J01 * gx1 + J02 * gx2);
                up1 = -(J10 * gx0 + J11 * gx1 + J12 * gx2);
                up2 = -(J20 * gx0 + J21 * gx1 + J22 * gx2);
            }
        }
        ++step;
    }
}

extern "C" void kernel_launch(void* const* d_in, const int* in_sizes, int n_in,
                              void* d_out, int out_size, void* d_ws, size_t ws_size,
                              hipStream_t stream) {
    const float* x = (const float*)d_in[0];
    const float* bone_pts = (const float*)d_in[1];
    const float* transforms = (const float*)d_in[2];
    const float* delta_tf = (const float*)d_in[3];
    const float* W0 = (const float*)d_in[4];
    const float* b0 = (const float*)d_in[5];
    const float* W1 = (const float*)d_in[6];
    const float* b1 = (const float*)d_in[7];
    const float* W2 = (const float*)d_in[8];
    const float* b2 = (const float*)d_in[9];
    const float* W3 = (const float*)d_in[10];
    const float* b3 = (const float*)d_in[11];
    const float* W4 = (const float*)d_in[12];
    const float* b4 = (const float*)d_in[13];
    float* out = (float*)d_out;

    float* W0p = (float*)d_ws;                 // 32*128 floats
    float* W4p = W0p + 32 * 128;               // 128*28 floats

    prep_kernel<<<16, 256, 0, stream>>>(W0, W4, W0p, W4p);

    const int Npts = in_sizes[0] / 3;
    const int M = Npts * 6;
    const int blocks = (M + BLOCK - 1) / BLOCK;
    snarf_kernel<<<blocks, BLOCK, 0, stream>>>(
        x, bone_pts, transforms, delta_tf, W0p, b0, W1, b1, W2, b2, W3, b3,
        W4p, b4, out, Npts);
}

// Round 3
// 7927.609 us; speedup vs baseline: 1.2387x; 1.2387x over previous
//
#include <hip/hip_runtime.h>
#include <math.h>

#define BLOCK 256  // 4 waves; 2 lanes per problem -> 128 problems/block

// prep: pad W4 [128][25] -> [128][32] (zero cols), b4 [25] -> [32]
__global__ void prep_kernel(const float* __restrict__ W4, const float* __restrict__ b4,
                            float* __restrict__ W4p, float* __restrict__ b4p) {
    const int t = blockIdx.x * blockDim.x + threadIdx.x;
    if (t < 128 * 32) {
        const int k = t >> 5, j = t & 31;
        W4p[t] = (j < 25) ? W4[k * 25 + j] : 0.0f;
    }
    if (t < 32) b4p[t] = (t < 25) ? b4[t] : 0.0f;
}

// o[0..63] += sum over 27 pe rows read from own LDS column (both halves hold full pe)
__device__ __forceinline__ void layer0(const float* __restrict__ Wme,  // W0 + s*64
                                       const float* __restrict__ bme,  // b0 + s*64
                                       const float* __restrict__ hA,   // &hL[tid]
                                       float* __restrict__ o) {
#pragma unroll
    for (int j = 0; j < 64; j += 4) {
        const float4 bb = *(const float4*)(bme + j);
        o[j] = bb.x; o[j + 1] = bb.y; o[j + 2] = bb.z; o[j + 3] = bb.w;
    }
#pragma unroll
    for (int jq = 0; jq < 4; ++jq) {
        float* __restrict__ oc = o + jq * 16;
        const float* __restrict__ Wq = Wme + jq * 16;
#pragma unroll 3
        for (int k = 0; k < 27; ++k) {
            const float h = hA[k * BLOCK];
            const float* Wr = Wq + k * 128;
            const float4 w0 = *(const float4*)(Wr + 0);
            const float4 w1 = *(const float4*)(Wr + 4);
            const float4 w2 = *(const float4*)(Wr + 8);
            const float4 w3 = *(const float4*)(Wr + 12);
            oc[0] = fmaf(h, w0.x, oc[0]);  oc[1] = fmaf(h, w0.y, oc[1]);
            oc[2] = fmaf(h, w0.z, oc[2]);  oc[3] = fmaf(h, w0.w, oc[3]);
            oc[4] = fmaf(h, w1.x, oc[4]);  oc[5] = fmaf(h, w1.y, oc[5]);
            oc[6] = fmaf(h, w1.z, oc[6]);  oc[7] = fmaf(h, w1.w, oc[7]);
            oc[8] = fmaf(h, w2.x, oc[8]);  oc[9] = fmaf(h, w2.y, oc[9]);
            oc[10] = fmaf(h, w2.z, oc[10]); oc[11] = fmaf(h, w2.w, oc[11]);
            oc[12] = fmaf(h, w3.x, oc[12]); oc[13] = fmaf(h, w3.y, oc[13]);
            oc[14] = fmaf(h, w3.z, oc[14]); oc[15] = fmaf(h, w3.w, oc[15]);
        }
    }
}

// square layer 128 -> my 64 outputs. Own col holds k in [rowA, rowA+64),
// partner col holds [rowB, rowB+64).
__device__ __forceinline__ void layer_sq(const float* __restrict__ Wme,  // W + s*64
                                         const float* __restrict__ bme,  // b + s*64
                                         const float* __restrict__ hA,   // &hL[tid]
                                         const float* __restrict__ hB,   // &hL[tid^32]
                                         const int rowA, const int rowB,
                                         float* __restrict__ o) {
#pragma unroll
    for (int j = 0; j < 64; j += 4) {
        const float4 bb = *(const float4*)(bme + j);
        o[j] = bb.x; o[j + 1] = bb.y; o[j + 2] = bb.z; o[j + 3] = bb.w;
    }
#pragma unroll
    for (int jq = 0; jq < 4; ++jq) {
        float* __restrict__ oc = o + jq * 16;
        const float* __restrict__ WA = Wme + rowA * 128 + jq * 16;
        const float* __restrict__ WB = Wme + rowB * 128 + jq * 16;
#pragma unroll 4
        for (int kp = 0; kp < 64; ++kp) {
            const float h = hA[kp * BLOCK];
            const float* Wr = WA + kp * 128;
            const float4 w0 = *(const float4*)(Wr + 0);
            const float4 w1 = *(const float4*)(Wr + 4);
            const float4 w2 = *(const float4*)(Wr + 8);
            const float4 w3 = *(const float4*)(Wr + 12);
            oc[0] = fmaf(h, w0.x, oc[0]);  oc[1] = fmaf(h, w0.y, oc[1]);
            oc[2] = fmaf(h, w0.z, oc[2]);  oc[3] = fmaf(h, w0.w, oc[3]);
            oc[4] = fmaf(h, w1.x, oc[4]);  oc[5] = fmaf(h, w1.y, oc[5]);
            oc[6] = fmaf(h, w1.z, oc[6]);  oc[7] = fmaf(h, w1.w, oc[7]);
            oc[8] = fmaf(h, w2.x, oc[8]);  oc[9] = fmaf(h, w2.y, oc[9]);
            oc[10] = fmaf(h, w2.z, oc[10]); oc[11] = fmaf(h, w2.w, oc[11]);
            oc[12] = fmaf(h, w3.x, oc[12]); oc[13] = fmaf(h, w3.y, oc[13]);
            oc[14] = fmaf(h, w3.z, oc[14]); oc[15] = fmaf(h, w3.w, oc[15]);
        }
#pragma unroll 4
        for (int kp = 0; kp < 64; ++kp) {
            const float h = hB[kp * BLOCK];
            const float* Wr = WB + kp * 128;
            const float4 w0 = *(const float4*)(Wr + 0);
            const float4 w1 = *(const float4*)(Wr + 4);
            const float4 w2 = *(const float4*)(Wr + 8);
            const float4 w3 = *(const float4*)(Wr + 12);
            oc[0] = fmaf(h, w0.x, oc[0]);  oc[1] = fmaf(h, w0.y, oc[1]);
            oc[2] = fmaf(h, w0.z, oc[2]);  oc[3] = fmaf(h, w0.w, oc[3]);
            oc[4] = fmaf(h, w1.x, oc[4]);  oc[5] = fmaf(h, w1.y, oc[5]);
            oc[6] = fmaf(h, w1.z, oc[6]);  oc[7] = fmaf(h, w1.w, oc[7]);
            oc[8] = fmaf(h, w2.x, oc[8]);  oc[9] = fmaf(h, w2.y, oc[9]);
            oc[10] = fmaf(h, w2.z, oc[10]); oc[11] = fmaf(h, w2.w, oc[11]);
            oc[12] = fmaf(h, w3.x, oc[12]); oc[13] = fmaf(h, w3.y, oc[13]);
            oc[14] = fmaf(h, w3.z, oc[14]); oc[15] = fmaf(h, w3.w, oc[15]);
        }
    }
}

// output layer 128 -> my 16 (of 32 padded) logits, W row stride 32
__device__ __forceinline__ void layer_out(const float* __restrict__ Wme,  // W4p + s*16
                                          const float* __restrict__ bme,  // b4p + s*16
                                          const float* __restrict__ hA,
                                          const float* __restrict__ hB,
                                          const int rowA, const int rowB,
                                          float* __restrict__ o) {
#pragma unroll
    for (int j = 0; j < 16; j += 4) {
        const float4 bb = *(const float4*)(bme + j);
        o[j] = bb.x; o[j + 1] = bb.y; o[j + 2] = bb.z; o[j + 3] = bb.w;
    }
#pragma unroll 4
    for (int kp = 0; kp < 64; ++kp) {
        const float h = hA[kp * BLOCK];
        const float* Wr = Wme + (rowA + kp) * 32;
        const float4 w0 = *(const float4*)(Wr + 0);
        const float4 w1 = *(const float4*)(Wr + 4);
        const float4 w2 = *(const float4*)(Wr + 8);
        const float4 w3 = *(const float4*)(Wr + 12);
        o[0] = fmaf(h, w0.x, o[0]);  o[1] = fmaf(h, w0.y, o[1]);
        o[2] = fmaf(h, w0.z, o[2]);  o[3] = fmaf(h, w0.w, o[3]);
        o[4] = fmaf(h, w1.x, o[4]);  o[5] = fmaf(h, w1.y, o[5]);
        o[6] = fmaf(h, w1.z, o[6]);  o[7] = fmaf(h, w1.w, o[7]);
        o[8] = fmaf(h, w2.x, o[8]);  o[9] = fmaf(h, w2.y, o[9]);
        o[10] = fmaf(h, w2.z, o[10]); o[11] = fmaf(h, w2.w, o[11]);
        o[12] = fmaf(h, w3.x, o[12]); o[13] = fmaf(h, w3.y, o[13]);
        o[14] = fmaf(h, w3.z, o[14]); o[15] = fmaf(h, w3.w, o[15]);
    }
#pragma unroll 4
    for (int kp = 0; kp < 64; ++kp) {
        const float h = hB[kp * BLOCK];
        const float* Wr = Wme + (rowB + kp) * 32;
        const float4 w0 = *(const float4*)(Wr + 0);
        const float4 w1 = *(const float4*)(Wr + 4);
        const float4 w2 = *(const float4*)(Wr + 8);
        const float4 w3 = *(const float4*)(Wr + 12);
        o[0] = fmaf(h, w0.x, o[0]);  o[1] = fmaf(h, w0.y, o[1]);
        o[2] = fmaf(h, w0.z, o[2]);  o[3] = fmaf(h, w0.w, o[3]);
        o[4] = fmaf(h, w1.x, o[4]);  o[5] = fmaf(h, w1.y, o[5]);
        o[6] = fmaf(h, w1.z, o[6]);  o[7] = fmaf(h, w1.w, o[7]);
        o[8] = fmaf(h, w2.x, o[8]);  o[9] = fmaf(h, w2.y, o[9]);
        o[10] = fmaf(h, w2.z, o[10]); o[11] = fmaf(h, w2.w, o[11]);
        o[12] = fmaf(h, w3.x, o[12]); o[13] = fmaf(h, w3.y, o[13]);
        o[14] = fmaf(h, w3.z, o[14]); o[15] = fmaf(h, w3.w, o[15]);
    }
}

__global__ __launch_bounds__(BLOCK, 2) void snarf_kernel(
    const float* __restrict__ xin, const float* __restrict__ bone_pts,
    const float* __restrict__ transforms, const float* __restrict__ delta_tf,
    const float* __restrict__ W0, const float* __restrict__ b0,
    const float* __restrict__ W1, const float* __restrict__ b1,
    const float* __restrict__ W2, const float* __restrict__ b2,
    const float* __restrict__ W3, const float* __restrict__ b3,
    const float* __restrict__ W4p, const float* __restrict__ b4p,
    float* __restrict__ out, int Npts) {
    __shared__ float hL[64 * BLOCK];  // [k'][tid], 64 KiB; column tid = my half
    const int tid = threadIdx.x;
    const int lane = tid & 63;
    const int s = (lane >> 5);  // which half of the pair
    const int M = Npts * 6;
    const int m = blockIdx.x * (BLOCK / 2) + (tid >> 6) * 32 + (lane & 31);
    if (m >= M) return;
    const int n = m / 6;
    const int i = m - n * 6;

    float* __restrict__ hme = &hL[tid];
    const float* __restrict__ hpa = &hL[tid ^ 32];
    const int rowA = s * 64, rowB = 64 - s * 64;

    const float* __restrict__ W0me = W0 + s * 64;
    const float* __restrict__ b0me = b0 + s * 64;
    const float* __restrict__ W4me = W4p + s * 16;
    const float* __restrict__ b4me = b4p + s * 16;

    const float tx = xin[n * 3 + 0], ty = xin[n * 3 + 1], tz = xin[n * 3 + 2];

    // ---- init candidate (duplicated on both pair lanes; bitwise identical)
    float xk0, xk1, xk2;
    if (i < 5) {
        float dprev = -1.0f;
        int jprev = -1;
        for (int r = 0; r <= i; ++r) {
            float bd = 3.4028235e38f;
            int bj = 0;
            for (int j = 0; j < 24; ++j) {
                const float ax = tx - bone_pts[j * 3 + 0];
                const float ay = ty - bone_pts[j * 3 + 1];
                const float az = tz - bone_pts[j * 3 + 2];
                const float d = sqrtf(ax * ax + ay * ay + az * az);
                const bool taken = (d < dprev) || (d == dprev && j <= jprev);
                if (!taken && d < bd) { bd = d; bj = j; }
            }
            dprev = bd;
            jprev = bj;
        }
        const float* T = delta_tf + jprev * 16;
        xk0 = fmaf(T[0], tx, fmaf(T[1], ty, fmaf(T[2], tz, T[3])));
        xk1 = fmaf(T[4], tx, fmaf(T[5], ty, fmaf(T[6], tz, T[7])));
        xk2 = fmaf(T[8], tx, fmaf(T[9], ty, fmaf(T[10], tz, T[11])));
    } else {
        xk0 = tx; xk1 = ty; xk2 = tz;
    }

    // ---- Broyden state (duplicated per pair lane)
    float gx0 = 0.f, gx1 = 0.f, gx2 = 0.f;
    float J00 = 1.f, J01 = 0.f, J02 = 0.f;
    float J10 = 0.f, J11 = 1.f, J12 = 0.f;
    float J20 = 0.f, J21 = 0.f, J22 = 1.f;
    float up0 = 0.f, up1 = 0.f, up2 = 0.f;
    float xo0 = xk0, xo1 = xk1, xo2 = xk2;
    float nopt = 0.f;
    float dx0 = 0.f, dx1 = 0.f, dx2 = 0.f;
    float dg0 = 0.f, dg1 = 0.f, dg2 = 0.f;
    bool mask = true;

    float o[64];
    float lg[32];

    int step = -1;  // -1 init eval, 0..7 Broyden, 8 final eval
    while (step <= 8) {
        bool m3 = mask;
        if (step >= 0 && step < 8) {
            if (__ballot(mask) == 0ull) { step = 8; continue; }
            if (m3) {
                dx0 = up0; dx1 = up1; dx2 = up2;
                xk0 += dx0; xk1 += dx1; xk2 += dx2;
            }
        }
        float cx0 = xk0, cx1 = xk1, cx2 = xk2;
        if (step == 8) { cx0 = xo0; cx1 = xo1; cx2 = xo2; }

        // ---- positional encoding into OWN column rows 0..26 (full pe per column)
        hme[0 * BLOCK] = cx0;
        hme[1 * BLOCK] = cx1;
        hme[2 * BLOCK] = cx2;
#pragma unroll
        for (int sc = 0; sc < 4; ++sc) {
            const float f = (float)(1 << sc);
            float s0, c0, s1, c1, s2, c2;
            sincosf(f * cx0, &s0, &c0);
            sincosf(f * cx1, &s1, &c1);
            sincosf(f * cx2, &s2, &c2);
            hme[(3 + sc * 3 + 0) * BLOCK] = s0;
            hme[(3 + sc * 3 + 1) * BLOCK] = s1;
            hme[(3 + sc * 3 + 2) * BLOCK] = s2;
            hme[(15 + sc * 3 + 0) * BLOCK] = c0;
            hme[(15 + sc * 3 + 1) * BLOCK] = c1;
            hme[(15 + sc * 3 + 2) * BLOCK] = c2;
        }

        layer0(W0me, b0me, hme, o);
#pragma unroll
        for (int j = 0; j < 64; ++j) hme[j * BLOCK] = fmaxf(o[j], 0.0f);

        layer_sq(W1 + s * 64, b1 + s * 64, hme, hpa, rowA, rowB, o);
#pragma unroll
        for (int j = 0; j < 64; ++j) hme[j * BLOCK] = fmaxf(o[j], 0.0f);

        layer_sq(W2 + s * 64, b2 + s * 64, hme, hpa, rowA, rowB, o);
#pragma unroll
        for (int j = 0; j < 64; ++j) hme[j * BLOCK] = fmaxf(o[j], 0.0f);

        layer_sq(W3 + s * 64, b3 + s * 64, hme, hpa, rowA, rowB, o);
#pragma unroll
        for (int j = 0; j < 64; ++j) hme[j * BLOCK] = fmaxf(o[j], 0.0f);

        layer_out(W4me, b4me, hme, hpa, rowA, rowB, o);

        // exchange logits through LDS rows 0..15 (h no longer needed)
#pragma unroll
        for (int j = 0; j < 16; ++j) hme[j * BLOCK] = o[j];
#pragma unroll
        for (int j = 0; j < 16; ++j) {
            const float pv = hpa[j * BLOCK];
            lg[j] = s ? pv : o[j];
            lg[16 + j] = s ? o[j] : pv;
        }

        // softmax(5 * logits) over 25 (duplicated per pair lane, identical)
        float zm = -3.4028235e38f;
#pragma unroll
        for (int j = 0; j < 25; ++j) {
            lg[j] = 5.0f * lg[j];
            zm = fmaxf(zm, lg[j]);
        }
        float ssum = 0.f;
#pragma unroll
        for (int j = 0; j < 25; ++j) {
            lg[j] = expf(lg[j] - zm);
            ssum += lg[j];
        }
        const float inv = 1.0f / ssum;

        float tf[12];
#pragma unroll
        for (int r = 0; r < 12; ++r) tf[r] = 0.f;
#pragma unroll
        for (int j = 0; j < 24; ++j) {
            const float wj = lg[j] * inv;
            const float* T = transforms + j * 16;
#pragma unroll
            for (int r = 0; r < 12; ++r) tf[r] = fmaf(wj, T[r], tf[r]);
        }
        {
            const float wj = lg[24] * inv;  // identity transform
            tf[0] += wj; tf[5] += wj; tf[10] += wj;
        }
        const float r0 = fmaf(tf[0], cx0, fmaf(tf[1], cx1, fmaf(tf[2], cx2, tf[3])));
        const float r1 = fmaf(tf[4], cx0, fmaf(tf[5], cx1, fmaf(tf[6], cx2, tf[7])));
        const float r2 = fmaf(tf[8], cx0, fmaf(tf[9], cx1, fmaf(tf[10], cx2, tf[11])));

        if (step == 8) {
            if (s == 0) {
                out[(size_t)m * 3 + 0] = r0;
                out[(size_t)m * 3 + 1] = r1;
                out[(size_t)m * 3 + 2] = r2;
                float* xopt_out = out + (size_t)M * 3;
                xopt_out[(size_t)m * 3 + 0] = xo0;
                xopt_out[(size_t)m * 3 + 1] = xo1;
                xopt_out[(size_t)m * 3 + 2] = xo2;
                out[(size_t)M * 6 + m] = nopt;
                out[(size_t)M * 7 + m] = (nopt < 1e-5f) ? 1.0f : 0.0f;
            }
            break;
        }

        const float g0 = r0 - tx, g1 = r1 - ty, g2 = r2 - tz;

        if (step == -1) {
            gx0 = g0; gx1 = g1; gx2 = g2;
            const float gn = sqrtf(g0 * g0 + g1 * g1 + g2 * g2);
            nopt = gn;
            up0 = -g0; up1 = -g1; up2 = -g2;  // Jinv = I
        } else {
            if (m3) {
                dg0 = g0 - gx0; dg1 = g1 - gx1; dg2 = g2 - gx2;
                gx0 += dg0; gx1 += dg1; gx2 += dg2;
            }
            const float gn = sqrtf(gx0 * gx0 + gx1 * gx1 + gx2 * gx2);
            const bool better = gn < nopt;
            if (better) {
                nopt = gn;
                xo0 = xk0; xo1 = xk1; xo2 = xk2;
            }
            mask = (nopt > 1e-5f) && (gn < 1.0f);

            const float v0 = dx0 * J00 + dx1 * J10 + dx2 * J20;
            const float v1 = dx0 * J01 + dx1 * J11 + dx2 * J21;
            const float v2 = dx0 * J02 + dx1 * J12 + dx2 * J22;
            const float Jd0 = J00 * dg0 + J01 * dg1 + J02 * dg2;
            const float Jd1 = J10 * dg0 + J11 * dg1 + J12 * dg2;
            const float Jd2 = J20 * dg0 + J21 * dg1 + J22 * dg2;
            const float a0 = dx0 - Jd0, a1 = dx1 - Jd1, a2 = dx2 - Jd2;
            float bden = v0 * dg0 + v1 * dg1 + v2 * dg2;
            bden += (bden >= 0.f) ? 1e-6f : -1e-6f;
            if (mask) {
                const float q0 = a0 / bden, q1 = a1 / bden, q2 = a2 / bden;
                J00 = fmaf(q0, v0, J00); J01 = fmaf(q0, v1, J01); J02 = fmaf(q0, v2, J02);
                J10 = fmaf(q1, v0, J10); J11 = fmaf(q1, v1, J11); J12 = fmaf(q1, v2, J12);
                J20 = fmaf(q2, v0, J20); J21 = fmaf(q2, v1, J21); J22 = fmaf(q2, v2, J22);
            }
            if (m3) {
                up0 = -(J00 * gx0 + J01 * gx1 + J02 * gx2);
                up1 = -(J10 * gx0 + J11 * gx1 + J12 * gx2);
                up2 = -(J20 * gx0 + J21 * gx1 + J22 * gx2);
            }
        }
        ++step;
    }
}

extern "C" void kernel_launch(void* const* d_in, const int* in_sizes, int n_in,
                              void* d_out, int out_size, void* d_ws, size_t ws_size,
                              hipStream_t stream) {
    const float* x = (const float*)d_in[0];
    const float* bone_pts = (const float*)d_in[1];
    const float* transforms = (const float*)d_in[2];
    const float* delta_tf = (const float*)d_in[3];
    const float* W0 = (const float*)d_in[4];
    const float* b0 = (const float*)d_in[5];
    const float* W1 = (const float*)d_in[6];
    const float* b1 = (const float*)d_in[7];
    const float* W2 = (const float*)d_in[8];
    const float* b2 = (const float*)d_in[9];
    const float* W3 = (const float*)d_in[10];
    const float* b3 = (const float*)d_in[11];
    const float* W4 = (const float*)d_in[12];
    const float* b4 = (const float*)d_in[13];
    float* out = (float*)d_out;

    float* W4p = (float*)d_ws;       // 128*32 floats
    float* b4p = W4p + 128 * 32;     // 32 floats

    prep_kernel<<<16, 256, 0, stream>>>(W4, b4, W4p, b4p);

    const int Npts = in_sizes[0] / 3;
    const int M = Npts * 6;
    const int blocks = (M + (BLOCK / 2) - 1) / (BLOCK / 2);
    snarf_kernel<<<blocks, BLOCK, 0, stream>>>(
        x, bone_pts, transforms, delta_tf, W0, b0, W1, b1, W2, b2, W3, b3,
        W4p, b4p, out, Npts);
}